// Round 1
// baseline (714.165 us; speedup 1.0000x reference)
//
#include <hip/hip_runtime.h>
#include <hip/hip_bf16.h>
#include <cstdint>
#include <cstddef>

// ---------------------------------------------------------------------------
// LlamaAttention forward: out = Attn(RoPE(x@wq), RoPE(x@wk), x@wv) @ wo
// B=2 T=2048 C=2048 NH=32 NKV=8 D=64, causal, GQA rep=4, scale=1/8.
// Strategy: bf16 MFMA everywhere, fp32 accum.
// ---------------------------------------------------------------------------

using bf16 = __hip_bfloat16;
using f32x4  = __attribute__((ext_vector_type(4))) float;
using short8 = __attribute__((ext_vector_type(8))) short;

typedef __attribute__((address_space(1))) const void* gp1_t;
typedef __attribute__((address_space(3))) void*       lp3_t;

#define GLOAD_LDS16(g, l)                                                     \
  __builtin_amdgcn_global_load_lds((gp1_t)(const void*)(g), (lp3_t)(void*)(l), 16, 0, 0)

static constexpr int Bd  = 2;
static constexpr int Td  = 2048;
static constexpr int Cd  = 2048;
static constexpr int NH  = 32;
static constexpr int NKV = 8;
static constexpr int HD  = 64;
static constexpr int Md  = Bd * Td;     // 4096 rows

__device__ inline float bf2f(unsigned short u) {
  union { unsigned int i; float f; } v; v.i = ((unsigned int)u) << 16; return v.f;
}
__device__ inline unsigned short f2bfbits(float f) {
  union { float f; unsigned int u; } v; v.f = f;
  unsigned int r = v.u + 0x7fffu + ((v.u >> 16) & 1u);   // RNE
  return (unsigned short)(r >> 16);
}

// ---------------- fp32 -> bf16 (vectorized) --------------------------------
__global__ __launch_bounds__(256) void f2b_kernel(const float* __restrict__ in,
                                                  bf16* __restrict__ out, int n4) {
  int i = blockIdx.x * 256 + threadIdx.x;
  if (i >= n4) return;
  float4 v = ((const float4*)in)[i];
  ushort4 o;
  o.x = f2bfbits(v.x); o.y = f2bfbits(v.y); o.z = f2bfbits(v.z); o.w = f2bfbits(v.w);
  ((ushort4*)out)[i] = o;
}

// ---------------- fp32 [R][Cc] -> bf16 transpose [Cc][R] -------------------
__global__ __launch_bounds__(256) void transpose_f2b(const float* __restrict__ in,
                                                     bf16* __restrict__ out,
                                                     int R, int Cc) {
  __shared__ float tile[32][33];
  int tx = threadIdx.x, ty = threadIdx.y;
  int bx = blockIdx.x, by = blockIdx.y;
  int col = bx * 32 + tx;
#pragma unroll
  for (int i = 0; i < 4; ++i) {
    int row = by * 32 + ty + i * 8;
    tile[ty + i * 8][tx] = in[(size_t)row * Cc + col];
  }
  __syncthreads();
#pragma unroll
  for (int i = 0; i < 4; ++i) {
    int orow = bx * 32 + ty + i * 8;   // original col
    int ocol = by * 32 + tx;           // original row
    out[(size_t)orow * R + ocol] = __float2bfloat16(tile[tx][ty + i * 8]);
  }
}

// ---------------- GEMM: C[M][N] = A[M][K] * Bt[N][K]^T ---------------------
// 128x128 tile, BK=32, 4 waves (2x2), 4x4 16x16 frags per wave.
// MODE 0: write bf16 head layout [B][nh][T][64]       (Q, K)
// MODE 1: write bf16 transposed  [B][nh][64][T]       (V)
// MODE 2: write fp32 row-major [M][N]                 (final out)
template <int MODE>
__global__ __launch_bounds__(256) void gemm_bf16(const bf16* __restrict__ A,
                                                 const bf16* __restrict__ Bt,
                                                 void* __restrict__ Cp,
                                                 int M, int N, int K, int nh) {
  __shared__ bf16 Al[128 * 32];
  __shared__ bf16 Bl[128 * 32];
  int tid = threadIdx.x;
  int w = tid >> 6, lane = tid & 63;
  int lr = lane & 15, lg = lane >> 4;
  int m0 = blockIdx.x * 128, n0 = blockIdx.y * 128;
  int wr = w >> 1, wc = w & 1;
  f32x4 acc[4][4] = {};

  const bf16* Aw = A + (size_t)m0 * K;
  const bf16* Bw = Bt + (size_t)n0 * K;
  int srow = (lane >> 2);          // 0..15 within segment
  int scol = (lane & 3) * 8;       // 0,8,16,24

  for (int kt = 0; kt < K; kt += 32) {
#pragma unroll
    for (int r = 0; r < 2; ++r) {
      int seg = r * 4 + w;                 // 0..7 -> 16 rows each
      int row = seg * 16 + srow;
      GLOAD_LDS16(Aw + (size_t)row * K + kt + scol, &Al[seg * 512]);
      GLOAD_LDS16(Bw + (size_t)row * K + kt + scol, &Bl[seg * 512]);
    }
    __syncthreads();
    short8 af[4], bfr[4];
#pragma unroll
    for (int f = 0; f < 4; ++f) {
      af[f]  = *(const short8*)&Al[(wr * 64 + f * 16 + lr) * 32 + lg * 8];
      bfr[f] = *(const short8*)&Bl[(wc * 64 + f * 16 + lr) * 32 + lg * 8];
    }
#pragma unroll
    for (int i = 0; i < 4; ++i)
#pragma unroll
      for (int j = 0; j < 4; ++j)
        acc[i][j] = __builtin_amdgcn_mfma_f32_16x16x32_bf16(af[i], bfr[j], acc[i][j], 0, 0, 0);
    __syncthreads();
  }

#pragma unroll
  for (int i = 0; i < 4; ++i) {
#pragma unroll
    for (int j = 0; j < 4; ++j) {
#pragma unroll
      for (int r = 0; r < 4; ++r) {
        int mrow = m0 + wr * 64 + i * 16 + lg * 4 + r;
        int ncol = n0 + wc * 64 + j * 16 + lr;
        float v = acc[i][j][r];
        if (MODE == 0) {
          int b = mrow >> 11, t = mrow & 2047;
          int h = ncol >> 6, d = ncol & 63;
          ((bf16*)Cp)[(((size_t)b * nh + h) * Td + t) * HD + d] = __float2bfloat16(v);
        } else if (MODE == 1) {
          int b = mrow >> 11, t = mrow & 2047;
          int h = ncol >> 6, d = ncol & 63;
          ((bf16*)Cp)[(((size_t)b * nh + h) * HD + d) * Td + t] = __float2bfloat16(v);
        } else {
          ((float*)Cp)[(size_t)mrow * N + ncol] = v;
        }
      }
    }
  }
}

// ---------------- RoPE (in-place on bf16 head-layout Q and K) --------------
__global__ __launch_bounds__(256) void rope_kernel(bf16* __restrict__ Q,
                                                   bf16* __restrict__ K,
                                                   int qpairs, int total) {
  int i = blockIdx.x * 256 + threadIdx.x;
  if (i >= total) return;
  unsigned int* buf; int p;
  if (i < qpairs) { buf = (unsigned int*)Q; p = i; }
  else            { buf = (unsigned int*)K; p = i - qpairs; }
  int d2 = p & 31;             // pair index within head dim (D/2 = 32)
  int t  = (p >> 5) & (Td - 1);
  unsigned int packed = buf[p];
  float xe = bf2f((unsigned short)(packed & 0xffffu));
  float xo = bf2f((unsigned short)(packed >> 16));
  float inv = powf(10000.0f, -(float)d2 / 32.0f);
  float ang = (float)t * inv;
  float s, c;
  sincosf(ang, &s, &c);
  float re = xe * c - xo * s;
  float ro = xo * c + xe * s;
  buf[p] = (unsigned int)f2bfbits(re) | ((unsigned int)f2bfbits(ro) << 16);
}

// ---------------- Flash attention (causal, GQA) ----------------------------
// grid (T/64, B*NH), 256 thr = 4 waves; wave w owns q rows qt*64+w*16 .. +15.
// K: [B][NKV][T][64] bf16 (post-RoPE), Vt: [B][NKV][64][T] bf16.
// Y out: bf16 [M][C] (= [B,T,NH*64]).
__global__ __launch_bounds__(256) void attn_kernel(const bf16* __restrict__ Q,
                                                   const bf16* __restrict__ K,
                                                   const bf16* __restrict__ Vt,
                                                   bf16* __restrict__ Y) {
  __shared__ bf16 Plds[4][16 * 64];
  int tid = threadIdx.x, w = tid >> 6, lane = tid & 63;
  int lr = lane & 15, lg = lane >> 4;
  int qt = blockIdx.x;
  int bh = blockIdx.y;
  int b = bh >> 5, h = bh & 31, kvh = h >> 2;
  int qrow0 = qt * 64 + w * 16;

  const bf16* Qp = Q + (((size_t)b * NH + h) * Td + qrow0) * HD;
  const bf16* Kp = K + (((size_t)b * NKV + kvh) * Td) * HD;
  const bf16* Vp = Vt + (((size_t)b * NKV + kvh) * HD) * Td;

  short8 qf[2];
  qf[0] = *(const short8*)(Qp + (size_t)lr * HD + lg * 8);
  qf[1] = *(const short8*)(Qp + (size_t)lr * HD + 32 + lg * 8);

  f32x4 o[4] = {};
  float mrow[4], lrow[4];
#pragma unroll
  for (int r = 0; r < 4; ++r) { mrow[r] = -1e30f; lrow[r] = 0.0f; }

  int nkv = qt + 1;
  for (int jt = 0; jt < nkv; ++jt) {
    int kvb = jt * 64;
    f32x4 s[4] = {};
#pragma unroll
    for (int ks = 0; ks < 2; ++ks) {
#pragma unroll
      for (int n = 0; n < 4; ++n) {
        short8 kf = *(const short8*)(Kp + (size_t)(kvb + n * 16 + lr) * HD + ks * 32 + lg * 8);
        s[n] = __builtin_amdgcn_mfma_f32_16x16x32_bf16(qf[ks], kf, s[n], 0, 0, 0);
      }
    }
    // scale + causal mask + row max
    float pm[4];
#pragma unroll
    for (int r = 0; r < 4; ++r) {
      int qg = qrow0 + lg * 4 + r;
      float mx = -1e30f;
#pragma unroll
      for (int n = 0; n < 4; ++n) {
        float v = s[n][r] * 0.125f;
        int kg = kvb + n * 16 + lr;
        if (kg > qg) v = -1e30f;
        s[n][r] = v;
        mx = fmaxf(mx, v);
      }
      pm[r] = mx;
    }
#pragma unroll
    for (int off = 1; off <= 8; off <<= 1) {
#pragma unroll
      for (int r = 0; r < 4; ++r) pm[r] = fmaxf(pm[r], __shfl_xor(pm[r], off));
    }
    float alpha[4];
#pragma unroll
    for (int r = 0; r < 4; ++r) {
      float mn = fmaxf(mrow[r], pm[r]);
      alpha[r] = expf(mrow[r] - mn);
      mrow[r] = mn;
    }
    float ps[4] = {0.f, 0.f, 0.f, 0.f};
#pragma unroll
    for (int n = 0; n < 4; ++n) {
#pragma unroll
      for (int r = 0; r < 4; ++r) {
        float p = expf(s[n][r] - mrow[r]);
        s[n][r] = p;
        ps[r] += p;
      }
    }
#pragma unroll
    for (int off = 1; off <= 8; off <<= 1) {
#pragma unroll
      for (int r = 0; r < 4; ++r) ps[r] += __shfl_xor(ps[r], off);
    }
#pragma unroll
    for (int r = 0; r < 4; ++r) lrow[r] = lrow[r] * alpha[r] + ps[r];
#pragma unroll
    for (int c = 0; c < 4; ++c)
#pragma unroll
      for (int r = 0; r < 4; ++r) o[c][r] *= alpha[r];
    // P -> LDS (bf16, S-layout -> A-layout roundtrip)
#pragma unroll
    for (int n = 0; n < 4; ++n)
#pragma unroll
      for (int r = 0; r < 4; ++r)
        Plds[w][(lg * 4 + r) * 64 + n * 16 + lr] = __float2bfloat16(s[n][r]);
    __syncthreads();
#pragma unroll
    for (int ks = 0; ks < 2; ++ks) {
      short8 pa = *(const short8*)&Plds[w][lr * 64 + ks * 32 + lg * 8];
#pragma unroll
      for (int c = 0; c < 4; ++c) {
        short8 vf = *(const short8*)(Vp + (size_t)(c * 16 + lr) * Td + kvb + ks * 32 + lg * 8);
        o[c] = __builtin_amdgcn_mfma_f32_16x16x32_bf16(pa, vf, o[c], 0, 0, 0);
      }
    }
    __syncthreads();
  }
  // epilogue: normalize, write Y[M][C]
#pragma unroll
  for (int c = 0; c < 4; ++c) {
#pragma unroll
    for (int r = 0; r < 4; ++r) {
      int t = qrow0 + lg * 4 + r;
      float val = o[c][r] / lrow[r];
      Y[((size_t)b * Td + t) * Cd + h * HD + c * 16 + lr] = __float2bfloat16(val);
    }
  }
}

// ---------------------------------------------------------------------------
extern "C" void kernel_launch(void* const* d_in, const int* in_sizes, int n_in,
                              void* d_out, int out_size, void* d_ws, size_t ws_size,
                              hipStream_t stream) {
  const float* x  = (const float*)d_in[0];
  const float* wq = (const float*)d_in[1];
  const float* wk = (const float*)d_in[2];
  const float* wv = (const float*)d_in[3];
  const float* wo = (const float*)d_in[4];

  char* ws = (char*)d_ws;
  const size_t o_xb = 0;                       // 16.78 MB (also reused as yb)
  const size_t o_w1 = o_xb + (size_t)Md * Cd * 2;        // 8.39 MB (wqT, later woT)
  const size_t o_w2 = o_w1 + (size_t)Cd * Cd * 2;        // 2.10 MB (wkT)
  const size_t o_w3 = o_w2 + (size_t)512 * Cd * 2;       // 2.10 MB (wvT)
  const size_t o_Q  = o_w3 + (size_t)512 * Cd * 2;       // 16.78 MB
  const size_t o_K  = o_Q + (size_t)Bd * NH * Td * HD * 2;   // 4.19 MB
  const size_t o_V  = o_K + (size_t)Bd * NKV * Td * HD * 2;  // 4.19 MB

  bf16* xb  = (bf16*)(ws + o_xb);
  bf16* w1  = (bf16*)(ws + o_w1);
  bf16* w2  = (bf16*)(ws + o_w2);
  bf16* w3  = (bf16*)(ws + o_w3);
  bf16* Qb  = (bf16*)(ws + o_Q);
  bf16* Kb  = (bf16*)(ws + o_K);
  bf16* Vtb = (bf16*)(ws + o_V);
  bf16* yb  = xb;   // alias: x_bf16 dead after V GEMM

  // 1. x -> bf16
  {
    int n4 = (Md * Cd) / 4;
    f2b_kernel<<<dim3((n4 + 255) / 256), dim3(256), 0, stream>>>(x, xb, n4);
  }
  // 2-4. weight transposes (fp32 -> bf16^T)
  transpose_f2b<<<dim3(Cd / 32, Cd / 32), dim3(32, 8), 0, stream>>>(wq, w1, Cd, Cd);
  transpose_f2b<<<dim3(512 / 32, Cd / 32), dim3(32, 8), 0, stream>>>(wk, w2, Cd, 512);
  transpose_f2b<<<dim3(512 / 32, Cd / 32), dim3(32, 8), 0, stream>>>(wv, w3, Cd, 512);
  // 5-7. QKV projections
  gemm_bf16<0><<<dim3(Md / 128, Cd / 128), dim3(256), 0, stream>>>(xb, w1, Qb, Md, Cd, Cd, NH);
  gemm_bf16<0><<<dim3(Md / 128, 512 / 128), dim3(256), 0, stream>>>(xb, w2, Kb, Md, 512, Cd, NKV);
  gemm_bf16<1><<<dim3(Md / 128, 512 / 128), dim3(256), 0, stream>>>(xb, w3, Vtb, Md, 512, Cd, NKV);
  // 8. wo transpose into w1 (wqT dead)
  transpose_f2b<<<dim3(Cd / 32, Cd / 32), dim3(32, 8), 0, stream>>>(wo, w1, Cd, Cd);
  // 9. RoPE on Q and K (in place)
  {
    int qpairs = Bd * NH * Td * HD / 2;
    int kpairs = Bd * NKV * Td * HD / 2;
    int total = qpairs + kpairs;
    rope_kernel<<<dim3((total + 255) / 256), dim3(256), 0, stream>>>(Qb, Kb, qpairs, total);
  }
  // 10. attention -> yb (bf16 [M][C])
  attn_kernel<<<dim3(Td / 64, Bd * NH), dim3(256), 0, stream>>>(Qb, Kb, Vtb, yb);
  // 11. output projection -> d_out (fp32)
  gemm_bf16<2><<<dim3(Md / 128, Cd / 128), dim3(256), 0, stream>>>(yb, w1, d_out, Md, Cd, Cd, 0);
}

// Round 2
// 436.969 us; speedup vs baseline: 1.6344x; 1.6344x over previous
//
#include <hip/hip_runtime.h>
#include <hip/hip_bf16.h>
#include <cstdint>
#include <cstddef>

// ---------------------------------------------------------------------------
// LlamaAttention forward: out = Attn(RoPE(x@wq), RoPE(x@wk), x@wv) @ wo
// B=2 T=2048 C=2048 NH=32 NKV=8 D=64, causal, GQA rep=4, scale=1/8.
// bf16 MFMA everywhere, fp32 accum.
// R2: attn rewrite — LPT-balanced grid, swizzled wave-private P LDS (no
// barriers), exp2-based softmax w/ prescaled Q, diag-only masking, T13
// defer-rescale. QKV projections merged into one GEMM (N=3072).
// ---------------------------------------------------------------------------

using bf16 = __hip_bfloat16;
using f32x4  = __attribute__((ext_vector_type(4))) float;
using short8 = __attribute__((ext_vector_type(8))) short;

typedef __attribute__((address_space(1))) const void* gp1_t;
typedef __attribute__((address_space(3))) void*       lp3_t;

#define GLOAD_LDS16(g, l)                                                     \
  __builtin_amdgcn_global_load_lds((gp1_t)(const void*)(g), (lp3_t)(void*)(l), 16, 0, 0)

static constexpr int Bd  = 2;
static constexpr int Td  = 2048;
static constexpr int Cd  = 2048;
static constexpr int NH  = 32;
static constexpr int NKV = 8;
static constexpr int HD  = 64;
static constexpr int Md  = Bd * Td;     // 4096 rows

__device__ inline float bf2f(unsigned short u) {
  union { unsigned int i; float f; } v; v.i = ((unsigned int)u) << 16; return v.f;
}
__device__ inline unsigned short f2bfbits(float f) {
  union { float f; unsigned int u; } v; v.f = f;
  unsigned int r = v.u + 0x7fffu + ((v.u >> 16) & 1u);   // RNE
  return (unsigned short)(r >> 16);
}

// ---------------- fp32 -> bf16 (vectorized) --------------------------------
__global__ __launch_bounds__(256) void f2b_kernel(const float* __restrict__ in,
                                                  bf16* __restrict__ out, int n4) {
  int i = blockIdx.x * 256 + threadIdx.x;
  if (i >= n4) return;
  float4 v = ((const float4*)in)[i];
  ushort4 o;
  o.x = f2bfbits(v.x); o.y = f2bfbits(v.y); o.z = f2bfbits(v.z); o.w = f2bfbits(v.w);
  ((ushort4*)out)[i] = o;
}

// ---------------- fp32 [R][Cc] -> bf16 transpose [Cc][R] -------------------
__global__ __launch_bounds__(256) void transpose_f2b(const float* __restrict__ in,
                                                     bf16* __restrict__ out,
                                                     int R, int Cc) {
  __shared__ float tile[32][33];
  int tx = threadIdx.x, ty = threadIdx.y;
  int bx = blockIdx.x, by = blockIdx.y;
  int col = bx * 32 + tx;
#pragma unroll
  for (int i = 0; i < 4; ++i) {
    int row = by * 32 + ty + i * 8;
    tile[ty + i * 8][tx] = in[(size_t)row * Cc + col];
  }
  __syncthreads();
#pragma unroll
  for (int i = 0; i < 4; ++i) {
    int orow = bx * 32 + ty + i * 8;   // original col
    int ocol = by * 32 + tx;           // original row
    out[(size_t)orow * R + ocol] = __float2bfloat16(tile[tx][ty + i * 8]);
  }
}

// ---------------- GEMM: C[M][N] = A[M][K] * Bt[N][K]^T ---------------------
// 128x128 tile, BK=32, 4 waves (2x2), 4x4 16x16 frags per wave.
// MODE 2: write fp32 row-major [M][N]              (final out)
// MODE 3: fused QKV epilogue — Cp = Qb base; Q head layout / K head layout /
//         V transposed, routed by n0 (region boundaries are 128-multiples).
template <int MODE>
__global__ __launch_bounds__(256) void gemm_bf16(const bf16* __restrict__ A,
                                                 const bf16* __restrict__ Bt,
                                                 void* __restrict__ Cp,
                                                 int M, int N, int K) {
  __shared__ bf16 Al[128 * 32];
  __shared__ bf16 Bl[128 * 32];
  int tid = threadIdx.x;
  int w = tid >> 6, lane = tid & 63;
  int lr = lane & 15, lg = lane >> 4;
  int m0 = blockIdx.x * 128, n0 = blockIdx.y * 128;
  int wr = w >> 1, wc = w & 1;
  f32x4 acc[4][4] = {};

  const bf16* Aw = A + (size_t)m0 * K;
  const bf16* Bw = Bt + (size_t)n0 * K;
  int srow = (lane >> 2);          // 0..15 within segment
  int scol = (lane & 3) * 8;       // 0,8,16,24

  for (int kt = 0; kt < K; kt += 32) {
#pragma unroll
    for (int r = 0; r < 2; ++r) {
      int seg = r * 4 + w;                 // 0..7 -> 16 rows each
      int row = seg * 16 + srow;
      GLOAD_LDS16(Aw + (size_t)row * K + kt + scol, &Al[seg * 512]);
      GLOAD_LDS16(Bw + (size_t)row * K + kt + scol, &Bl[seg * 512]);
    }
    __syncthreads();
    short8 af[4], bfr[4];
#pragma unroll
    for (int f = 0; f < 4; ++f) {
      af[f]  = *(const short8*)&Al[(wr * 64 + f * 16 + lr) * 32 + lg * 8];
      bfr[f] = *(const short8*)&Bl[(wc * 64 + f * 16 + lr) * 32 + lg * 8];
    }
#pragma unroll
    for (int i = 0; i < 4; ++i)
#pragma unroll
      for (int j = 0; j < 4; ++j)
        acc[i][j] = __builtin_amdgcn_mfma_f32_16x16x32_bf16(af[i], bfr[j], acc[i][j], 0, 0, 0);
    __syncthreads();
  }

  bf16* Qb  = (bf16*)Cp;
  bf16* Kb  = Qb + (size_t)Bd * NH * Td * HD;
  bf16* Vtb = Kb + (size_t)Bd * NKV * Td * HD;

#pragma unroll
  for (int i = 0; i < 4; ++i) {
#pragma unroll
    for (int j = 0; j < 4; ++j) {
#pragma unroll
      for (int r = 0; r < 4; ++r) {
        int mrow = m0 + wr * 64 + i * 16 + lg * 4 + r;
        int ncol = n0 + wc * 64 + j * 16 + lr;
        float v = acc[i][j][r];
        if (MODE == 2) {
          ((float*)Cp)[(size_t)mrow * N + ncol] = v;
        } else {
          int b = mrow >> 11, t = mrow & 2047;
          if (n0 < 2048) {             // Q: [B][32][T][64]
            int h = ncol >> 6, d = ncol & 63;
            Qb[(((size_t)b * NH + h) * Td + t) * HD + d] = __float2bfloat16(v);
          } else if (n0 < 2560) {      // K: [B][8][T][64]
            int cc = ncol - 2048;
            int h = cc >> 6, d = cc & 63;
            Kb[(((size_t)b * NKV + h) * Td + t) * HD + d] = __float2bfloat16(v);
          } else {                     // V^T: [B][8][64][T]
            int cc = ncol - 2560;
            int h = cc >> 6, d = cc & 63;
            Vtb[(((size_t)b * NKV + h) * HD + d) * Td + t] = __float2bfloat16(v);
          }
        }
      }
    }
  }
}

// ---------------- RoPE (in-place on bf16 head-layout Q and K) --------------
__global__ __launch_bounds__(256) void rope_kernel(bf16* __restrict__ Q,
                                                   bf16* __restrict__ K,
                                                   int qpairs, int total) {
  int i = blockIdx.x * 256 + threadIdx.x;
  if (i >= total) return;
  unsigned int* buf; int p;
  if (i < qpairs) { buf = (unsigned int*)Q; p = i; }
  else            { buf = (unsigned int*)K; p = i - qpairs; }
  int d2 = p & 31;             // pair index within head dim (D/2 = 32)
  int t  = (p >> 5) & (Td - 1);
  unsigned int packed = buf[p];
  float xe = bf2f((unsigned short)(packed & 0xffffu));
  float xo = bf2f((unsigned short)(packed >> 16));
  float inv = powf(10000.0f, -(float)d2 / 32.0f);
  float ang = (float)t * inv;
  float s, c;
  sincosf(ang, &s, &c);
  float re = xe * c - xo * s;
  float ro = xo * c + xe * s;
  buf[p] = (unsigned int)f2bfbits(re) | ((unsigned int)f2bfbits(ro) << 16);
}

// ---------------- Flash attention (causal, GQA) ----------------------------
// grid (B*NH=64, T/64=32), 256 thr = 4 independent waves (no block barriers).
// LPT: qt = 31 - blockIdx.y so heavy blocks dispatch first.
// Q prescaled by 0.125*log2(e); softmax in exp2 domain.
// K: [B][NKV][T][64] bf16 (post-RoPE), Vt: [B][NKV][64][T] bf16.
// Y out: bf16 [M][C] (= [B,T,NH*64]).
__global__ __launch_bounds__(256) void attn_kernel(const bf16* __restrict__ Q,
                                                   const bf16* __restrict__ K,
                                                   const bf16* __restrict__ Vt,
                                                   bf16* __restrict__ Y) {
  __shared__ bf16 Plds[4][16 * 64];      // wave-private, XOR-swizzled
  int tid = threadIdx.x, w = tid >> 6, lane = tid & 63;
  int lr = lane & 15, lg = lane >> 4;
  int qt = (int)gridDim.y - 1 - (int)blockIdx.y;   // heavy first
  int bh = blockIdx.x;
  int b = bh >> 5, h = bh & 31, kvh = h >> 2;
  int qrow0 = qt * 64 + w * 16;

  const bf16* Qp = Q + (((size_t)b * NH + h) * Td + qrow0) * HD;
  const bf16* Kp = K + (((size_t)b * NKV + kvh) * Td) * HD;
  const bf16* Vp = Vt + (((size_t)b * NKV + kvh) * HD) * Td;
  bf16* Pw = &Plds[w][0];

  const float SC = 0.125f * 1.44269504f;   // fold scale + log2(e) into Q
  short8 qf[2];
  {
    short8 q0 = *(const short8*)(Qp + (size_t)lr * HD + lg * 8);
    short8 q1 = *(const short8*)(Qp + (size_t)lr * HD + 32 + lg * 8);
#pragma unroll
    for (int e = 0; e < 8; ++e) {
      qf[0][e] = (short)f2bfbits(bf2f((unsigned short)q0[e]) * SC);
      qf[1][e] = (short)f2bfbits(bf2f((unsigned short)q1[e]) * SC);
    }
  }

  f32x4 o[4] = {};
  float mrow[4], lrow[4];
#pragma unroll
  for (int r = 0; r < 4; ++r) { mrow[r] = -3e38f; lrow[r] = 0.0f; }

  for (int jt = 0; jt <= qt; ++jt) {
    int kvb = jt * 64;
    f32x4 s[4] = {};
#pragma unroll
    for (int ks = 0; ks < 2; ++ks) {
#pragma unroll
      for (int n = 0; n < 4; ++n) {
        short8 kf = *(const short8*)(Kp + (size_t)(kvb + n * 16 + lr) * HD + ks * 32 + lg * 8);
        s[n] = __builtin_amdgcn_mfma_f32_16x16x32_bf16(qf[ks], kf, s[n], 0, 0, 0);
      }
    }
    if (jt == qt) {    // only diagonal tile needs causal masking
#pragma unroll
      for (int r = 0; r < 4; ++r) {
        int qg = qrow0 + lg * 4 + r;
#pragma unroll
        for (int n = 0; n < 4; ++n) {
          int kg = kvb + n * 16 + lr;
          if (kg > qg) s[n][r] = -3e38f;
        }
      }
    }
    float pm[4];
#pragma unroll
    for (int r = 0; r < 4; ++r)
      pm[r] = fmaxf(fmaxf(s[0][r], s[1][r]), fmaxf(s[2][r], s[3][r]));
#pragma unroll
    for (int off = 1; off <= 8; off <<= 1)
#pragma unroll
      for (int r = 0; r < 4; ++r) pm[r] = fmaxf(pm[r], __shfl_xor(pm[r], off));

    bool grow = (pm[0] > mrow[0]) | (pm[1] > mrow[1]) |
                (pm[2] > mrow[2]) | (pm[3] > mrow[3]);
    if (__any(grow)) {                      // T13: rescale only on max growth
      float alpha[4];
#pragma unroll
      for (int r = 0; r < 4; ++r) {
        float mn = fmaxf(mrow[r], pm[r]);
        alpha[r] = exp2f(mrow[r] - mn);
        mrow[r] = mn;
        lrow[r] *= alpha[r];
      }
#pragma unroll
      for (int c = 0; c < 4; ++c)
#pragma unroll
        for (int r = 0; r < 4; ++r) o[c][r] *= alpha[r];
    }
    float ps[4] = {0.f, 0.f, 0.f, 0.f};
#pragma unroll
    for (int n = 0; n < 4; ++n)
#pragma unroll
      for (int r = 0; r < 4; ++r) {
        float p = exp2f(s[n][r] - mrow[r]);
        s[n][r] = p;
        ps[r] += p;
      }
#pragma unroll
    for (int off = 1; off <= 8; off <<= 1)
#pragma unroll
      for (int r = 0; r < 4; ++r) ps[r] += __shfl_xor(ps[r], off);
#pragma unroll
    for (int r = 0; r < 4; ++r) lrow[r] += ps[r];

    // P -> wave-private LDS (XOR-swizzled: elem ^= (row&7)<<3; G4 recipe)
#pragma unroll
    for (int n = 0; n < 4; ++n)
#pragma unroll
      for (int r = 0; r < 4; ++r) {
        int row = lg * 4 + r;
        Pw[(row * 64 + n * 16 + lr) ^ ((row & 7) << 3)] = __float2bfloat16(s[n][r]);
      }
    asm volatile("s_waitcnt lgkmcnt(0)" ::: "memory");
    __builtin_amdgcn_sched_barrier(0);
#pragma unroll
    for (int ks = 0; ks < 2; ++ks) {
      short8 pa = *(const short8*)&Pw[(lr * 64 + ks * 32 + lg * 8) ^ ((lr & 7) << 3)];
#pragma unroll
      for (int c = 0; c < 4; ++c) {
        short8 vf = *(const short8*)(Vp + (size_t)(c * 16 + lr) * Td + kvb + ks * 32 + lg * 8);
        o[c] = __builtin_amdgcn_mfma_f32_16x16x32_bf16(pa, vf, o[c], 0, 0, 0);
      }
    }
    __builtin_amdgcn_sched_barrier(0);
  }
  // epilogue: normalize, write Y[M][C]
#pragma unroll
  for (int c = 0; c < 4; ++c) {
#pragma unroll
    for (int r = 0; r < 4; ++r) {
      int t = qrow0 + lg * 4 + r;
      float val = o[c][r] / lrow[r];
      Y[((size_t)b * Td + t) * Cd + h * HD + c * 16 + lr] = __float2bfloat16(val);
    }
  }
}

// ---------------------------------------------------------------------------
extern "C" void kernel_launch(void* const* d_in, const int* in_sizes, int n_in,
                              void* d_out, int out_size, void* d_ws, size_t ws_size,
                              hipStream_t stream) {
  const float* x  = (const float*)d_in[0];
  const float* wq = (const float*)d_in[1];
  const float* wk = (const float*)d_in[2];
  const float* wv = (const float*)d_in[3];
  const float* wo = (const float*)d_in[4];

  char* ws = (char*)d_ws;
  const size_t o_xb = 0;                                   // 16.78 MB (reused as yb)
  const size_t o_w1 = o_xb + (size_t)Md * Cd * 2;          // 12.58 MB (wqkvT / later woT)
  const size_t o_Q  = o_w1 + (size_t)3072 * Cd * 2;        // 16.78 MB
  const size_t o_K  = o_Q + (size_t)Bd * NH * Td * HD * 2; // 4.19 MB
  const size_t o_V  = o_K + (size_t)Bd * NKV * Td * HD * 2;// 4.19 MB

  bf16* xb  = (bf16*)(ws + o_xb);
  bf16* w1  = (bf16*)(ws + o_w1);
  bf16* Qb  = (bf16*)(ws + o_Q);
  bf16* Kb  = (bf16*)(ws + o_K);
  bf16* Vtb = (bf16*)(ws + o_V);
  bf16* yb  = xb;   // alias: x_bf16 dead after QKV GEMM

  // 1. x -> bf16
  {
    int n4 = (Md * Cd) / 4;
    f2b_kernel<<<dim3((n4 + 255) / 256), dim3(256), 0, stream>>>(x, xb, n4);
  }
  // 2. weight transposes (fp32 -> bf16^T) into one [3072][2048] buffer
  transpose_f2b<<<dim3(Cd / 32, Cd / 32), dim3(32, 8), 0, stream>>>(wq, w1, Cd, Cd);
  transpose_f2b<<<dim3(512 / 32, Cd / 32), dim3(32, 8), 0, stream>>>(wk, w1 + (size_t)2048 * Cd, Cd, 512);
  transpose_f2b<<<dim3(512 / 32, Cd / 32), dim3(32, 8), 0, stream>>>(wv, w1 + (size_t)2560 * Cd, Cd, 512);
  // 3. fused QKV projection (N = 3072)
  gemm_bf16<3><<<dim3(Md / 128, 3072 / 128), dim3(256), 0, stream>>>(xb, w1, Qb, Md, 3072, Cd);
  // 4. wo transpose into w1 (wqkvT dead after GEMM)
  transpose_f2b<<<dim3(Cd / 32, Cd / 32), dim3(32, 8), 0, stream>>>(wo, w1, Cd, Cd);
  // 5. RoPE on Q and K (in place)
  {
    int qpairs = Bd * NH * Td * HD / 2;
    int kpairs = Bd * NKV * Td * HD / 2;
    int total = qpairs + kpairs;
    rope_kernel<<<dim3((total + 255) / 256), dim3(256), 0, stream>>>(Qb, Kb, qpairs, total);
  }
  // 6. attention -> yb (bf16 [M][C]); LPT-ordered balanced grid
  attn_kernel<<<dim3(Bd * NH, Td / 64), dim3(256), 0, stream>>>(Qb, Kb, Vtb, yb);
  // 7. output projection -> d_out (fp32)
  gemm_bf16<2><<<dim3(Md / 128, Cd / 128), dim3(256), 0, stream>>>(yb, w1, d_out, Md, Cd, Cd);
}

// Round 3
// 301.627 us; speedup vs baseline: 2.3677x; 1.4487x over previous
//
#include <hip/hip_runtime.h>
#include <hip/hip_bf16.h>
#include <cstdint>
#include <cstddef>

// ---------------------------------------------------------------------------
// LlamaAttention forward: out = Attn(RoPE(x@wq), RoPE(x@wk), x@wv) @ wo
// B=2 T=2048 C=2048 NH=32 NKV=8 D=64, causal, GQA rep=4, scale=1/8.
// R3: attn -> swapped-QK^T 32x32x16 structure (m214-style): in-register
// softmax (row lane-local), cvt_pk+shfl P redistribution (T12), O^T PV,
// defer-rescale (T13), no LDS, no barriers, setprio (T5). RoPE -> native
// exp2/v_sin/v_cos.
// ---------------------------------------------------------------------------

using bf16 = __hip_bfloat16;
using f32x4  = __attribute__((ext_vector_type(4))) float;
using f32x16 = __attribute__((ext_vector_type(16))) float;
using short8 = __attribute__((ext_vector_type(8))) short;
using u32x4  = __attribute__((ext_vector_type(4))) unsigned int;

typedef __attribute__((address_space(1))) const void* gp1_t;
typedef __attribute__((address_space(3))) void*       lp3_t;

#define GLOAD_LDS16(g, l)                                                     \
  __builtin_amdgcn_global_load_lds((gp1_t)(const void*)(g), (lp3_t)(void*)(l), 16, 0, 0)

#define MFMA32(a, b, c) __builtin_amdgcn_mfma_f32_32x32x16_bf16(a, b, c, 0, 0, 0)

static constexpr int Bd  = 2;
static constexpr int Td  = 2048;
static constexpr int Cd  = 2048;
static constexpr int NH  = 32;
static constexpr int NKV = 8;
static constexpr int HD  = 64;
static constexpr int Md  = Bd * Td;     // 4096 rows

__device__ inline float bf2f(unsigned short u) {
  union { unsigned int i; float f; } v; v.i = ((unsigned int)u) << 16; return v.f;
}
__device__ inline unsigned short f2bfbits(float f) {
  union { float f; unsigned int u; } v; v.f = f;
  unsigned int r = v.u + 0x7fffu + ((v.u >> 16) & 1u);   // RNE
  return (unsigned short)(r >> 16);
}
__device__ inline unsigned int pkbf(float a, float b) {   // lo=bf16(a), hi=bf16(b)
  unsigned int r;
  asm("v_cvt_pk_bf16_f32 %0, %1, %2" : "=v"(r) : "v"(a), "v"(b));
  return r;
}
__device__ inline float hmax16(const f32x16& v) {
  float a0 = fmaxf(v[0], v[1]),   a1 = fmaxf(v[2], v[3]);
  float a2 = fmaxf(v[4], v[5]),   a3 = fmaxf(v[6], v[7]);
  float a4 = fmaxf(v[8], v[9]),   a5 = fmaxf(v[10], v[11]);
  float a6 = fmaxf(v[12], v[13]), a7 = fmaxf(v[14], v[15]);
  float b0 = fmaxf(a0, a1), b1 = fmaxf(a2, a3);
  float b2 = fmaxf(a4, a5), b3 = fmaxf(a6, a7);
  return fmaxf(fmaxf(b0, b1), fmaxf(b2, b3));
}
__device__ inline float hsum16(const f32x16& v) {
  float a0 = v[0]+v[1],   a1 = v[2]+v[3],   a2 = v[4]+v[5],   a3 = v[6]+v[7];
  float a4 = v[8]+v[9],   a5 = v[10]+v[11], a6 = v[12]+v[13], a7 = v[14]+v[15];
  float b0 = a0+a1, b1 = a2+a3, b2 = a4+a5, b3 = a6+a7;
  return (b0+b1)+(b2+b3);
}

// ---------------- fp32 -> bf16 (vectorized) --------------------------------
__global__ __launch_bounds__(256) void f2b_kernel(const float* __restrict__ in,
                                                  bf16* __restrict__ out, int n4) {
  int i = blockIdx.x * 256 + threadIdx.x;
  if (i >= n4) return;
  float4 v = ((const float4*)in)[i];
  ushort4 o;
  o.x = f2bfbits(v.x); o.y = f2bfbits(v.y); o.z = f2bfbits(v.z); o.w = f2bfbits(v.w);
  ((ushort4*)out)[i] = o;
}

// ---------------- fp32 [R][Cc] -> bf16 transpose [Cc][R] -------------------
__global__ __launch_bounds__(256) void transpose_f2b(const float* __restrict__ in,
                                                     bf16* __restrict__ out,
                                                     int R, int Cc) {
  __shared__ float tile[32][33];
  int tx = threadIdx.x, ty = threadIdx.y;
  int bx = blockIdx.x, by = blockIdx.y;
  int col = bx * 32 + tx;
#pragma unroll
  for (int i = 0; i < 4; ++i) {
    int row = by * 32 + ty + i * 8;
    tile[ty + i * 8][tx] = in[(size_t)row * Cc + col];
  }
  __syncthreads();
#pragma unroll
  for (int i = 0; i < 4; ++i) {
    int orow = bx * 32 + ty + i * 8;   // original col
    int ocol = by * 32 + tx;           // original row
    out[(size_t)orow * R + ocol] = __float2bfloat16(tile[tx][ty + i * 8]);
  }
}

// ---------------- GEMM: C[M][N] = A[M][K] * Bt[N][K]^T ---------------------
// 128x128 tile, BK=32, 4 waves (2x2), 4x4 16x16 frags per wave.
// MODE 2: fp32 row-major [M][N].  MODE 3: fused QKV epilogue.
template <int MODE>
__global__ __launch_bounds__(256) void gemm_bf16(const bf16* __restrict__ A,
                                                 const bf16* __restrict__ Bt,
                                                 void* __restrict__ Cp,
                                                 int M, int N, int K) {
  __shared__ bf16 Al[128 * 32];
  __shared__ bf16 Bl[128 * 32];
  int tid = threadIdx.x;
  int w = tid >> 6, lane = tid & 63;
  int lr = lane & 15, lg = lane >> 4;
  int m0 = blockIdx.x * 128, n0 = blockIdx.y * 128;
  int wr = w >> 1, wc = w & 1;
  f32x4 acc[4][4] = {};

  const bf16* Aw = A + (size_t)m0 * K;
  const bf16* Bw = Bt + (size_t)n0 * K;
  int srow = (lane >> 2);          // 0..15 within segment
  int scol = (lane & 3) * 8;       // 0,8,16,24

  for (int kt = 0; kt < K; kt += 32) {
#pragma unroll
    for (int r = 0; r < 2; ++r) {
      int seg = r * 4 + w;                 // 0..7 -> 16 rows each
      int row = seg * 16 + srow;
      GLOAD_LDS16(Aw + (size_t)row * K + kt + scol, &Al[seg * 512]);
      GLOAD_LDS16(Bw + (size_t)row * K + kt + scol, &Bl[seg * 512]);
    }
    __syncthreads();
    short8 af[4], bfr[4];
#pragma unroll
    for (int f = 0; f < 4; ++f) {
      af[f]  = *(const short8*)&Al[(wr * 64 + f * 16 + lr) * 32 + lg * 8];
      bfr[f] = *(const short8*)&Bl[(wc * 64 + f * 16 + lr) * 32 + lg * 8];
    }
#pragma unroll
    for (int i = 0; i < 4; ++i)
#pragma unroll
      for (int j = 0; j < 4; ++j)
        acc[i][j] = __builtin_amdgcn_mfma_f32_16x16x32_bf16(af[i], bfr[j], acc[i][j], 0, 0, 0);
    __syncthreads();
  }

  bf16* Qb  = (bf16*)Cp;
  bf16* Kb  = Qb + (size_t)Bd * NH * Td * HD;
  bf16* Vtb = Kb + (size_t)Bd * NKV * Td * HD;

#pragma unroll
  for (int i = 0; i < 4; ++i) {
#pragma unroll
    for (int j = 0; j < 4; ++j) {
#pragma unroll
      for (int r = 0; r < 4; ++r) {
        int mrow = m0 + wr * 64 + i * 16 + lg * 4 + r;
        int ncol = n0 + wc * 64 + j * 16 + lr;
        float v = acc[i][j][r];
        if (MODE == 2) {
          ((float*)Cp)[(size_t)mrow * N + ncol] = v;
        } else {
          int b = mrow >> 11, t = mrow & 2047;
          if (n0 < 2048) {             // Q: [B][32][T][64]
            int h = ncol >> 6, d = ncol & 63;
            Qb[(((size_t)b * NH + h) * Td + t) * HD + d] = __float2bfloat16(v);
          } else if (n0 < 2560) {      // K: [B][8][T][64]
            int cc = ncol - 2048;
            int h = cc >> 6, d = cc & 63;
            Kb[(((size_t)b * NKV + h) * Td + t) * HD + d] = __float2bfloat16(v);
          } else {                     // V^T: [B][8][64][T]
            int cc = ncol - 2560;
            int h = cc >> 6, d = cc & 63;
            Vtb[(((size_t)b * NKV + h) * HD + d) * Td + t] = __float2bfloat16(v);
          }
        }
      }
    }
  }
}

// ---------------- RoPE (in-place, native trig) -----------------------------
__global__ __launch_bounds__(256) void rope_kernel(bf16* __restrict__ Q,
                                                   bf16* __restrict__ K,
                                                   int qpairs, int total) {
  int i = blockIdx.x * 256 + threadIdx.x;
  if (i >= total) return;
  unsigned int* buf; int p;
  if (i < qpairs) { buf = (unsigned int*)Q; p = i; }
  else            { buf = (unsigned int*)K; p = i - qpairs; }
  int d2 = p & 31;             // pair index within head dim (D/2 = 32)
  int t  = (p >> 5) & (Td - 1);
  unsigned int packed = buf[p];
  float xe = bf2f((unsigned short)(packed & 0xffffu));
  float xo = bf2f((unsigned short)(packed >> 16));
  // inv_freq = 10000^(-d2/32) = exp2(-d2 * log2(10000)/32)
  float inv = __builtin_amdgcn_exp2f((float)d2 * (-13.287712379549449f / 32.0f));
  float ang = (float)t * inv;
  float rev = ang * 0.15915494309189535f;     // radians -> revolutions
  rev = rev - floorf(rev);
  float s = __builtin_amdgcn_sinf(rev);
  float c = __builtin_amdgcn_cosf(rev);
  float re = xe * c - xo * s;
  float ro = xo * c + xe * s;
  buf[p] = (unsigned int)f2bfbits(re) | ((unsigned int)f2bfbits(ro) << 16);
}

// ---------------- Flash attention (causal, GQA), swapped-QK 32x32 ----------
// grid (B*NH=64, T/64=32), 128 thr = 2 independent waves, QBLK=32/wave.
// LPT: qt = 31 - blockIdx.y (heavy blocks first).
// Per lane: q = q0 + (lane&31) fixed; softmax state lane-local.
// S^T = mfma(K, Q): row=kv=(rr&3)+8*(rr>>2)+4*(lane>>5), col=q=lane&31.
// O^T = mfma(V^T, P): row=d (same formula), col=q.
// K: [B][NKV][T][64] bf16 (post-RoPE), Vt: [B][NKV][64][T] bf16.
__global__ __launch_bounds__(128) void attn_kernel(const bf16* __restrict__ Q,
                                                   const bf16* __restrict__ K,
                                                   const bf16* __restrict__ Vt,
                                                   bf16* __restrict__ Y) {
  int tid = threadIdx.x, w = tid >> 6, lane = tid & 63;
  int lq = lane & 31;          // q column
  int H  = lane >> 5;          // lane half
  int qt = 31 - (int)blockIdx.y;
  int bh = blockIdx.x;
  int b = bh >> 5, h = bh & 31, kvh = h >> 2;
  int q0 = qt * 64 + w * 32;
  int qg = q0 + lq;

  const bf16* Qp = Q + (((size_t)b * NH + h) * Td) * HD;
  const bf16* Kp = K + (((size_t)b * NKV + kvh) * Td) * HD;
  const bf16* Vp = Vt + (((size_t)b * NKV + kvh) * HD) * Td;

  // Q B-fragments (prescaled by 1/8 * log2(e)): qf[ck][j] = Q[qg][ck*16+H*8+j]
  const float SC = 0.125f * 1.44269504f;
  short8 qf[4];
#pragma unroll
  for (int ck = 0; ck < 4; ++ck) {
    short8 qv = *(const short8*)(Qp + (size_t)qg * HD + ck * 16 + H * 8);
#pragma unroll
    for (int e = 0; e < 8; ++e)
      qf[ck][e] = (short)f2bfbits(bf2f((unsigned short)qv[e]) * SC);
  }

  f32x16 acc0 = {}, acc1 = {};     // O^T[d][q], d-tiles 0..31 / 32..63
  float m = -3e38f, l = 0.0f;

  int nkv = (q0 >> 6) + 1;
  for (int jt = 0; jt < nkv; ++jt) {
    int kvb = jt * 64;
    // ---- S^T = K . Q^T  (2 kv-tiles x 4 k-chunks) ----
    f32x16 s0 = {}, s1 = {};
    const bf16* K0 = Kp + (size_t)(kvb + lq) * HD + H * 8;
    __builtin_amdgcn_s_setprio(1);
#pragma unroll
    for (int ck = 0; ck < 4; ++ck) {
      short8 kf0 = *(const short8*)(K0 + ck * 16);
      short8 kf1 = *(const short8*)(K0 + (size_t)32 * HD + ck * 16);
      s0 = MFMA32(kf0, qf[ck], s0);
      s1 = MFMA32(kf1, qf[ck], s1);
    }
    __builtin_amdgcn_s_setprio(0);
    // ---- causal mask (last tile only) ----
    if (jt == nkv - 1) {
#pragma unroll
      for (int rr = 0; rr < 16; ++rr) {
        int krel = (rr & 3) + 8 * (rr >> 2) + 4 * H;
        if (kvb + krel > qg)      s0[rr] = -3e38f;
        if (kvb + 32 + krel > qg) s1[rr] = -3e38f;
      }
    }
    // ---- row max: in-register tree + one cross-half exchange ----
    float mx = fmaxf(hmax16(s0), hmax16(s1));
    mx = fmaxf(mx, __shfl_xor(mx, 32));
    // ---- defer-rescale (T13, THR=8 in log2 domain) ----
    if (__any(mx > m + 8.0f)) {
      float mn = fmaxf(m, mx);
      float al = __builtin_amdgcn_exp2f(m - mn);
      m = mn;
      l *= al;
#pragma unroll
      for (int rr = 0; rr < 16; ++rr) { acc0[rr] *= al; acc1[rr] *= al; }
    }
    // ---- p = exp2(s - m) (masked -> 0 via underflow) ----
#pragma unroll
    for (int rr = 0; rr < 16; ++rr) {
      s0[rr] = __builtin_amdgcn_exp2f(s0[rr] - m);
      s1[rr] = __builtin_amdgcn_exp2f(s1[rr] - m);
    }
    float ps = hsum16(s0) + hsum16(s1);
    ps += __shfl_xor(ps, 32);
    l += ps;
    // ---- pack P to bf16 B-fragments: cvt_pk + cross-half shfl (T12) ----
    // frag[ks] word j needs P[q][16ks+8H+j]; source reg (j&3)+8*(ks&1)+4H
    // from half j>>2.
    unsigned int wds[4][4];
#pragma unroll
    for (int t = 0; t < 2; ++t) {
      const f32x16& sv = t ? s1 : s0;
#pragma unroll
      for (int a = 0; a < 2; ++a) {
        unsigned int A0 = pkbf(sv[8*a + 0], sv[8*a + 1]);
        unsigned int A1 = pkbf(sv[8*a + 2], sv[8*a + 3]);
        unsigned int B0 = pkbf(sv[8*a + 4], sv[8*a + 5]);
        unsigned int B1 = pkbf(sv[8*a + 6], sv[8*a + 7]);
        unsigned int sd0 = H ? A0 : B0;
        unsigned int sd1 = H ? A1 : B1;
        unsigned int x0 = (unsigned int)__shfl_xor((int)sd0, 32);
        unsigned int x1 = (unsigned int)__shfl_xor((int)sd1, 32);
        int ks = 2 * t + a;
        wds[ks][0] = H ? x0 : A0;
        wds[ks][1] = H ? x1 : A1;
        wds[ks][2] = H ? B0 : x0;
        wds[ks][3] = H ? B1 : x1;
      }
    }
    short8 pf[4];
#pragma unroll
    for (int ks = 0; ks < 4; ++ks) {
      u32x4 t4;
      t4[0] = wds[ks][0]; t4[1] = wds[ks][1];
      t4[2] = wds[ks][2]; t4[3] = wds[ks][3];
      pf[ks] = __builtin_bit_cast(short8, t4);
    }
    // ---- O^T += V^T . P  (2 d-tiles x 4 kv-chunks) ----
    const bf16* V0 = Vp + (size_t)lq * Td + kvb + H * 8;
    __builtin_amdgcn_s_setprio(1);
#pragma unroll
    for (int ks = 0; ks < 4; ++ks) {
      short8 vf0 = *(const short8*)(V0 + ks * 16);
      short8 vf1 = *(const short8*)(V0 + (size_t)32 * Td + ks * 16);
      acc0 = MFMA32(vf0, pf[ks], acc0);
      acc1 = MFMA32(vf1, pf[ks], acc1);
    }
    __builtin_amdgcn_s_setprio(0);
  }
  // ---- epilogue: normalize (l lane-local), write Y[M][C] ----
  float rn = 1.0f / l;
  bf16* Yp = Y + ((size_t)b * Td + qg) * Cd + h * HD;
#pragma unroll
  for (int rr = 0; rr < 16; rr += 2) {
    int d = (rr & 3) + 8 * (rr >> 2) + 4 * H;   // d, d+1 for rr, rr+1
    unsigned int w0 = pkbf(acc0[rr] * rn, acc0[rr + 1] * rn);
    unsigned int w1 = pkbf(acc1[rr] * rn, acc1[rr + 1] * rn);
    *(unsigned int*)(Yp + d)      = w0;
    *(unsigned int*)(Yp + 32 + d) = w1;
  }
}

// ---------------------------------------------------------------------------
extern "C" void kernel_launch(void* const* d_in, const int* in_sizes, int n_in,
                              void* d_out, int out_size, void* d_ws, size_t ws_size,
                              hipStream_t stream) {
  const float* x  = (const float*)d_in[0];
  const float* wq = (const float*)d_in[1];
  const float* wk = (const float*)d_in[2];
  const float* wv = (const float*)d_in[3];
  const float* wo = (const float*)d_in[4];

  char* ws = (char*)d_ws;
  const size_t o_xb = 0;                                   // 16.78 MB (reused as yb)
  const size_t o_w1 = o_xb + (size_t)Md * Cd * 2;          // 12.58 MB (wqkvT / later woT)
  const size_t o_Q  = o_w1 + (size_t)3072 * Cd * 2;        // 16.78 MB
  const size_t o_K  = o_Q + (size_t)Bd * NH * Td * HD * 2; // 4.19 MB
  const size_t o_V  = o_K + (size_t)Bd * NKV * Td * HD * 2;// 4.19 MB

  bf16* xb  = (bf16*)(ws + o_xb);
  bf16* w1  = (bf16*)(ws + o_w1);
  bf16* Qb  = (bf16*)(ws + o_Q);
  bf16* Kb  = (bf16*)(ws + o_K);
  bf16* Vtb = (bf16*)(ws + o_V);
  bf16* yb  = xb;   // alias: x_bf16 dead after QKV GEMM

  // 1. x -> bf16
  {
    int n4 = (Md * Cd) / 4;
    f2b_kernel<<<dim3((n4 + 255) / 256), dim3(256), 0, stream>>>(x, xb, n4);
  }
  // 2. weight transposes (fp32 -> bf16^T) into one [3072][2048] buffer
  transpose_f2b<<<dim3(Cd / 32, Cd / 32), dim3(32, 8), 0, stream>>>(wq, w1, Cd, Cd);
  transpose_f2b<<<dim3(512 / 32, Cd / 32), dim3(32, 8), 0, stream>>>(wk, w1 + (size_t)2048 * Cd, Cd, 512);
  transpose_f2b<<<dim3(512 / 32, Cd / 32), dim3(32, 8), 0, stream>>>(wv, w1 + (size_t)2560 * Cd, Cd, 512);
  // 3. fused QKV projection (N = 3072)
  gemm_bf16<3><<<dim3(Md / 128, 3072 / 128), dim3(256), 0, stream>>>(xb, w1, Qb, Md, 3072, Cd);
  // 4. wo transpose into w1 (wqkvT dead after GEMM)
  transpose_f2b<<<dim3(Cd / 32, Cd / 32), dim3(32, 8), 0, stream>>>(wo, w1, Cd, Cd);
  // 5. RoPE on Q and K (in place)
  {
    int qpairs = Bd * NH * Td * HD / 2;
    int kpairs = Bd * NKV * Td * HD / 2;
    int total = qpairs + kpairs;
    rope_kernel<<<dim3((total + 255) / 256), dim3(256), 0, stream>>>(Qb, Kb, qpairs, total);
  }
  // 6. attention -> yb (bf16 [M][C]); 2-wave blocks, LPT order
  attn_kernel<<<dim3(Bd * NH, Td / 64), dim3(128), 0, stream>>>(Qb, Kb, Vtb, yb);
  // 7. output projection -> d_out (fp32)
  gemm_bf16<2><<<dim3(Md / 128, Cd / 128), dim3(256), 0, stream>>>(yb, w1, d_out, Md, Cd, Cd);
}